// Round 22
// baseline (141.454 us; speedup 1.0000x reference)
//
#include <hip/hip_runtime.h>

#define TT    2000
#define NG    4000
#define WARM  365
#define LENF  15
#define NPHY  12
#define BLK   60                  // timesteps per staged block
#define PAIRS (BLK / 2)
#define SLOTW 64                  // dwords per step: 16 cells x {P,T,ev,ev}
#define SLOT  (BLK * SLOTW)       // 3840 dwords per stage slot
#define NBLK  34                  // 34*60 = 2040 steps (covers TT, stores gated)
#define ROWF  (3 * NG)            // floats per timestep row

typedef const float __attribute__((address_space(1)))* gptr_t;
typedef float __attribute__((address_space(3)))* lptr_t;
typedef __attribute__((ext_vector_type(2))) float f32x2;
typedef __attribute__((ext_vector_type(4))) float f32x4;

// Quad-wide sum via DPP (VALU-only). All 4 lanes of a quad get the sum.
__device__ __forceinline__ float quad_sum(float x) {
    int a = __builtin_amdgcn_update_dpp(0, __float_as_int(x), 0xB1, 0xF, 0xF, true);
    float s = x + __int_as_float(a);
    int b = __builtin_amdgcn_update_dpp(0, __float_as_int(s), 0x4E, 0xF, 0xF, true);
    return s + __int_as_float(b);
}

#define WG_BARRIER() asm volatile("s_waitcnt lgkmcnt(0)\n\ts_barrier" ::: "memory")

// r22 = r14 staging discipline + r20 slim wave structure, separating r20's
// two confounded effects (exec faster / fetch worse):
//   - stage layout: 4 dwords per cell {P,T,ev,ev} via size-4 gload_lds with
//     per-lane comp=min(lane&3,2) (duplicate ev dword = same cacheline ->
//     NO over-fetch, unlike r20's size-16). One load stages one step.
//   - wave0: ONE ds_read_b128/step + snow chain + {rt,ev} f32x4 ring.
//   - wave1: ring-only (no stage access), 0.5 b128/step, soil chain, b64 out.
//   - wave2/wave3: r14 bodies verbatim. Stage ring 2-deep (only wave0 reads).
//   - all 4 waves stage 15 steps/block, drain own vmcnt, barrier (r14-proven).
__global__ __launch_bounds__(256, 1) void hbv_pipe_kernel(
    const float* __restrict__ xphy,   // [T, G, 3]
    const float* __restrict__ prm,    // [1, G, 50]
    float* __restrict__ out)          // [T-WARM, G]
{
    __shared__ float s_stage[2 * SLOT];          // 30720 B, 2-slot ring
    __shared__ f32x4 s_rtev[2 * PAIRS * 64];     // {rtE,evE,rtO,evO} 61440 B
    __shared__ f32x2 s_rex [2 * PAIRS * 64];     // rex pairs         30720 B
    __shared__ f32x2 s_q   [2 * PAIRS * 64];     // q pairs           30720 B

    const int lane = threadIdx.x & 63;
    const int wid  = threadIdx.x >> 6;    // 0..3
    const int g0   = blockIdx.x * 16;     // 250 WGs * 16 cells
    const int cell = lane >> 2;
    const int g    = g0 + cell;
    const int m    = lane & 3;

    const float* pg = prm + (size_t)g * (NPHY * 4 + 2);

    const float lb[NPHY] = {1.0f, 50.0f, 0.05f, 0.01f, 0.001f, 0.2f, 0.0f, 0.0f, -2.5f, 0.5f, 0.0f, 0.0f};
    const float ub[NPHY] = {6.0f, 1000.0f, 0.9f, 0.5f, 0.2f, 1.0f, 10.0f, 100.0f, 2.5f, 10.0f, 0.1f, 0.2f};
    float ph[NPHY];
    #pragma unroll
    for (int i = 0; i < NPHY; ++i)
        ph[i] = lb[i] + pg[i * 4 + m] * (ub[i] - lb[i]);

    const float beta = ph[0], fc = ph[1], k0 = ph[2], k1 = ph[3], k2 = ph[4],
                lp = ph[5], perc = ph[6], uzl = ph[7], ttp = ph[8],
                cfmax = ph[9], cfr = ph[10], cwh = ph[11];
    const float rlpfc  = 1.0f / (lp * fc);
    const float cfrcf  = cfr * cfmax;
    const float blfc   = beta * __builtin_amdgcn_logf(1.0f / fc);
    const float onemk1 = 1.0f - k1;
    const float onemk2 = 1.0f - k2;

    // Routing weights (gammaln / th^aa cancel under normalization); 0.25 folded.
    const float aa  = fmaxf(pg[48] * 2.9f, 0.0f) + 0.1f;
    const float th  = fmaxf(pg[49] * 6.5f, 0.0f) + 0.5f;
    const float rth = 1.0f / th;
    const float LOG2E = 1.4426950408889634f;
    float w[LENF];
    float wsum = 0.0f;
    #pragma unroll
    for (int k = 0; k < LENF; ++k) {
        const float tg = (float)k + 0.5f;
        const float e = (aa - 1.0f) * __builtin_log2f(tg) - tg * rth * LOG2E;
        w[k] = __builtin_amdgcn_exp2f(e);
        wsum += w[k];
    }
    const float rw = 0.25f / wsum;
    #pragma unroll
    for (int k = 0; k < LENF; ++k) w[k] *= rw;

    // Per-wave persistent states
    float snowpack = 0.001f, meltwater = 0.001f;   // wave0
    float sm = 0.001f;                             // wave1
    float suz = 0.001f, slz = 0.001f;              // wave2
    float qh[BLK + LENF - 1];                      // wave3: q history (static idx)
    #pragma unroll
    for (int d = 0; d < BLK + LENF - 1; ++d) qh[d] = 0.0f;

    // staging lane map: cell = lane>>2, comp = min(lane&3, 2)  (dup ev dword,
    // same cacheline -> no extra HBM fetch; LDS gets {P,T,ev,ev} per cell)
    const int loffc = (lane >> 2) * 3 + ((lane & 3) < 2 ? (lane & 3) : 2);

    // each wave stages 15 steps of block b; one gload_lds per step
    auto stage_blk = [&](int b) {
        const int tb = b * BLK + wid * 15;
        float* ldst = &s_stage[(b & 1) * SLOT + (wid * 15) * SLOTW];
        #pragma unroll
        for (int c = 0; c < 15; ++c) {
            int t = tb + c; t = (t < TT) ? t : (TT - 1);
            const float* src = xphy + (size_t)t * ROWF + g0 * 3 + loffc;
            __builtin_amdgcn_global_load_lds((gptr_t)src, (lptr_t)(ldst + c * SLOTW), 4, 0, 0);
        }
    };

    stage_blk(0);
    asm volatile("s_waitcnt vmcnt(0)" ::: "memory");
    WG_BARRIER();

    for (int i = 0; i <= NBLK + 2; ++i) {
        if (i + 1 < NBLK) stage_blk(i + 1);   // lands by end-of-iter drain

        if (wid == 0) {
            // ---- snow chain, block i: 1 b128/step, pack {rt,ev} f32x4 ----
            if (i < NBLK) {
                const f32x4* sb = (const f32x4*)&s_stage[(i & 1) * SLOT + cell * 4];
                f32x4* rtw = &s_rtev[(i & 1) * (PAIRS * 64) + lane];
                float rtE = 0.0f, evE = 0.0f;
                #pragma unroll
                for (int j = 0; j < BLK; ++j) {
                    const f32x4 x = sb[j * 16];           // {P, T, ev, ev}
                    const float Pt = x[0], Tm = x[1], ev = x[2];
                    const float dT      = Tm - ttp;
                    const float rain    = (Tm >= ttp) ? Pt : 0.0f;
                    const float snw     = Pt - rain;
                    const float meltcap = cfmax * fmaxf(dT, 0.0f);
                    const float refcap  = cfrcf * fmaxf(-dT, 0.0f);
                    snowpack += snw;
                    const float melt = fminf(meltcap, snowpack);
                    meltwater += melt;
                    snowpack  -= melt;
                    const float refreeze = fminf(refcap, meltwater);
                    meltwater -= refreeze;
                    snowpack  += refreeze;
                    const float tosoil = fmaxf(fmaf(-cwh, snowpack, meltwater), 0.0f);
                    meltwater -= tosoil;
                    const float rt = rain + tosoil;
                    if ((j & 1) == 0) { rtE = rt; evE = ev; }
                    else {
                        f32x4 q; q[0] = rtE; q[1] = evE; q[2] = rt; q[3] = ev;
                        rtw[(j >> 1) * 64] = q;
                    }
                }
            }
        } else if (wid == 1) {
            // ---- soil chain, block i-1: ring-only, no stage access ----
            const int b = i - 1;
            if (b >= 0 && b < NBLK) {
                const f32x4* rtr = &s_rtev[(b & 1) * (PAIRS * 64) + lane];
                f32x2* rexw = &s_rex[(b & 1) * (PAIRS * 64) + lane];
                f32x4 rp; rp[0] = 0.0f; rp[1] = 0.0f; rp[2] = 0.0f; rp[3] = 0.0f;
                float rexE = 0.0f;
                #pragma unroll
                for (int j = 0; j < BLK; ++j) {
                    if ((j & 1) == 0) rp = rtr[(j >> 1) * 64];
                    const float rt = ((j & 1) == 0) ? rp[0] : rp[2];
                    const float ev = ((j & 1) == 0) ? rp[1] : rp[3];
                    const float sw  = __builtin_amdgcn_exp2f(fmaf(beta, __builtin_amdgcn_logf(sm), blfc));
                    const float sp  = sm + rt;
                    const float sm1 = fmaf(-rt, sw, sp);
                    const float sm2 = fminf(sm1, fc);
                    const float uf  = fmaxf(fmaf(-ev, rlpfc, 1.0f), 0.0f);
                    sm = fmaxf(fmaxf(sm2 * uf, sm2 - ev), 1e-5f);   // v_max3
                    const float rex = fmaf(rt, sw, sm1 - sm2);
                    if ((j & 1) == 0) rexE = rex;
                    else { f32x2 pr; pr[0] = rexE; pr[1] = rex; rexw[(j >> 1) * 64] = pr; }
                }
            }
        } else if (wid == 2) {
            // ---- response chain + quad mean, block i-2 (r14 body) ----
            const int b = i - 2;
            if (b >= 0 && b < NBLK) {
                const f32x2* rexr = &s_rex[(b & 1) * (PAIRS * 64) + lane];
                f32x2* qw = &s_q[(b & 1) * (PAIRS * 64) + lane];
                f32x2 rp; rp[0] = 0.0f; rp[1] = 0.0f;
                float qE = 0.0f;
                #pragma unroll
                for (int j = 0; j < BLK; ++j) {
                    if ((j & 1) == 0) rp = rexr[(j >> 1) * 64];
                    const float rex = ((j & 1) == 0) ? rp[0] : rp[1];
                    const float suz1 = suz + rex;
                    const float prc  = fminf(suz1, perc);
                    const float suzA = suz1 - prc;
                    const float tq   = fmaxf(suzA - uzl, 0.0f);
                    const float q0   = k0 * tq;
                    const float suzB = fmaf(-k0, tq, suzA);
                    const float q1   = k1 * suzB;
                    suz = suzB * onemk1;
                    const float sl1  = slz + prc;
                    const float q2   = k2 * sl1;
                    slz = sl1 * onemk2;
                    const float q = quad_sum(q0 + q1 + q2);   // *0.25 folded in w
                    if ((j & 1) == 0) qE = q;
                    else { f32x2 pr; pr[0] = qE; pr[1] = q; qw[(j >> 1) * 64] = pr; }
                }
            }
        } else {
            // ---- 15-tap conv (gather form) + stores, block i-3 (r14 body) ----
            const int b = i - 3;
            if (b >= 0 && b < NBLK) {
                const int t0 = b * BLK;
                const f32x2* qr = &s_q[(b & 1) * (PAIRS * 64) + lane];
                #pragma unroll
                for (int jp = 0; jp < PAIRS; ++jp) {
                    const f32x2 qp = qr[jp * 64];
                    qh[LENF - 1 + 2 * jp]     = qp[0];
                    qh[LENF - 1 + 2 * jp + 1] = qp[1];
                }
                float ov[BLK / 4];
                #pragma unroll
                for (int k = 0; k < BLK / 4; ++k) ov[k] = 0.0f;
                #pragma unroll
                for (int j = 0; j < BLK; ++j) {
                    float o = w[0] * qh[LENF - 1 + j];
                    #pragma unroll
                    for (int k = 1; k < LENF; ++k)
                        o = fmaf(w[k], qh[LENF - 1 + j - k], o);
                    const bool sel = ((j & 3) == m);
                    ov[j >> 2] = sel ? o : ov[j >> 2];     // j>>2 compile-time
                }
                #pragma unroll
                for (int d = 0; d < LENF - 1; ++d) qh[d] = qh[d + BLK];   // static shift
                #pragma unroll
                for (int k = 0; k < BLK / 4; ++k) {
                    const int j = k * 4 + m;
                    const int t = t0 + j;
                    if (t >= WARM && t < TT)
                        out[(size_t)(t - WARM) * NG + g] = ov[k];
                }
            }
        }

        // drain own staging loads, then sync (r14 discipline)
        asm volatile("s_waitcnt vmcnt(0)" ::: "memory");
        WG_BARRIER();
    }
}

extern "C" void kernel_launch(void* const* d_in, const int* in_sizes, int n_in,
                              void* d_out, int out_size, void* d_ws, size_t ws_size,
                              hipStream_t stream) {
    const float* xphy = (const float*)d_in[0];   // [2000, 4000, 3]
    const float* prm  = (const float*)d_in[1];   // [1, 4000, 50]
    float* out = (float*)d_out;                  // [1635, 4000, 1]

    hbv_pipe_kernel<<<NG / 16, 256, 0, stream>>>(xphy, prm, out);
}